// Round 8
// baseline (4372.915 us; speedup 1.0000x reference)
//
#include <hip/hip_runtime.h>
#include <hip/hip_bf16.h>

typedef unsigned short u16;
typedef unsigned int u32;
typedef unsigned long long u64;
typedef __attribute__((ext_vector_type(8))) short short8v;      // MFMA bf16 frag (4 VGPR)
typedef __attribute__((ext_vector_type(8))) unsigned short ushort8v;
typedef __attribute__((ext_vector_type(4))) float float4v;
typedef __attribute__((ext_vector_type(4))) unsigned int uint4v;

#define S_LEN 1024
#define BATCH 256
#define VOCAB 32000
#define EMBED 512
#define HIDDEN 1024
#define BH (BATCH * HIDDEN)
#define FLAG_STRIDE 32   // u32s; 128B-pad flags so producer stores hit distinct L3 lines

__device__ inline u16 f2bf(float f) {
  return __builtin_bit_cast(u16, __float2bfloat16(f));  // RNE
}

// Coherent (sc0|sc1 = cpol 17: L2-bypass, L3 coherent point) 16B ops.
__device__ inline short8v cohload16(const u16* base, int voff) {
  __amdgpu_buffer_rsrc_t r =
      __builtin_amdgcn_make_buffer_rsrc((void*)base, (short)0, -1, 0x00020000);
  uint4v d = __builtin_amdgcn_raw_buffer_load_b128(r, voff, 0, 17);
  return __builtin_bit_cast(short8v, d);
}
__device__ inline void cohstore16(u16* base, int voff, ushort8v v) {
  __amdgpu_buffer_rsrc_t r =
      __builtin_amdgcn_make_buffer_rsrc((void*)base, (short)0, -1, 0x00020000);
  __builtin_amdgcn_raw_buffer_store_b128(__builtin_bit_cast(uint4v, v), r, voff, 0, 17);
}

__device__ inline short8v cvt8(float4v a, float4v b) {
  ushort8v v;
  v[0]=f2bf(a[0]); v[1]=f2bf(a[1]); v[2]=f2bf(a[2]); v[3]=f2bf(a[3]);
  v[4]=f2bf(b[0]); v[5]=f2bf(b[1]); v[6]=f2bf(b[2]); v[7]=f2bf(b[3]);
  return __builtin_bit_cast(short8v, v);
}

// ---------------- prep: zero hbuf + flags ----------------
__global__ __launch_bounds__(256) void prep_kernel(u16* __restrict__ hbuf,
                                                   u32* __restrict__ flag) {
  int i = blockIdx.x * 256 + threadIdx.x;
  const int NH = (2 * BH) / 8;   // 65536 chunks of 8 u16
  const int NF = (256 * FLAG_STRIDE) / 8;  // 1024 chunks (u32 x8 = 16B x2)... zero as u16x8
  ushort8v z = {0,0,0,0,0,0,0,0};
  if (i < NH) {
    *(ushort8v*)(hbuf + (size_t)i * 8) = z;
  } else if (i < NH + 2048) {
    // flag area: 256*32 u32 = 32KB = 2048 chunks of 16B
    *(ushort8v*)((u16*)flag + (size_t)(i - NH) * 8) = z;
  }
}

// ---------------- fused recurrence + input projection ----------------
// 256 persistent blocks = 16 groups (16 batch rows) x 16 col-tiles (64 cols).
// Per wave (k-split x4):
//   Wf  [4][8]: W_hh[64 cols][k-quarter]  in VGPR (128 VGPR)
//   Wihf[4][4]: W_ih[64 cols][k-quarter of EMBED] in VGPR (64 VGPR)
// Per step: emb-gather(t+1) issued before poll; h-GEMM on top of xp-partials;
// 4-wave LDS reduce; tanh; fp32 out + coherent bf16 h store; flag publish;
// xp-MFMA(t+1) off critical path. Exchange protocol identical to R7.
__global__ __launch_bounds__(256, 1) void rnn_fused(const int* __restrict__ xseq,
                                                    const float* __restrict__ emb,
                                                    const float* __restrict__ wih,
                                                    const float* __restrict__ bih,
                                                    const float* __restrict__ whh,
                                                    const float* __restrict__ bhh,
                                                    u16* __restrict__ hbuf,
                                                    float* __restrict__ out,
                                                    u32* __restrict__ flag) {
  __shared__ float red[4][16][68];   // [wave][row][col] fp32, +4 pad (2-way banks max)
  const int tid = threadIdx.x;
  const int lane = tid & 63, w = tid >> 6;
  const int l15 = lane & 15, l4 = lane >> 4;
  const int g = blockIdx.x & 15;             // batch rows [g*16, g*16+16)
  const int jt = blockIdx.x >> 4;            // hidden cols [jt*64, jt*64+64)

  // ---- prologue: weights into registers (static indexing throughout) ----
  short8v Wf[4][8];   // W_hh[col jj][k w*256 + kq*32 + l4*8]
  #pragma unroll
  for (int jj = 0; jj < 4; jj++)
    #pragma unroll
    for (int kq = 0; kq < 8; kq++) {
      const float* s = whh + (size_t)(jt * 64 + jj * 16 + l15) * HIDDEN
                       + w * 256 + kq * 32 + l4 * 8;
      Wf[jj][kq] = cvt8(*(const float4v*)s, *(const float4v*)(s + 4));
    }
  short8v Wihf[4][4]; // W_ih[col jj][k w*128 + kk*32 + l4*8]
  #pragma unroll
  for (int jj = 0; jj < 4; jj++)
    #pragma unroll
    for (int kk = 0; kk < 4; kk++) {
      const float* s = wih + (size_t)(jt * 64 + jj * 16 + l15) * EMBED
                       + w * 128 + kk * 32 + l4 * 8;
      Wihf[jj][kk] = cvt8(*(const float4v*)s, *(const float4v*)(s + 4));
    }
  // epilogue constants (threads 0..127 own row r, cols c0..c0+8)
  const int r = tid >> 3;
  const int c0 = (tid & 7) * 8;
  float bsum[8];
  #pragma unroll
  for (int i = 0; i < 8; i++) bsum[i] = bhh[jt * 64 + c0 + i] + bih[jt * 64 + c0 + i];
  const int aoff = ((g * 16 + l15) * HIDDEN + w * 256 + l4 * 8) * 2;  // h-frag byte off

  // ---- xp-partials for t=0 ----
  float4v xacc[4] = {};
  {
    int idx0 = xseq[g * 16 + l15];
    const float* er = emb + (size_t)idx0 * EMBED + w * 128 + l4 * 8;
    #pragma unroll
    for (int kk = 0; kk < 4; kk++) {
      short8v af = cvt8(*(const float4v*)(er + kk * 32), *(const float4v*)(er + kk * 32 + 4));
      #pragma unroll
      for (int jj = 0; jj < 4; jj++)
        xacc[jj] = __builtin_amdgcn_mfma_f32_16x16x32_bf16(af, Wihf[jj][kk], xacc[jj], 0, 0, 0);
    }
  }
  __syncthreads();  // red not yet used; aligns waves after prologue

  for (int t = 0; t < S_LEN; t++) {
    const int p = t & 1;
    float* outt = out + (size_t)t * BH;
    // consume xp-partials
    float4v accp[4] = {xacc[0], xacc[1], xacc[2], xacc[3]};
    // issue emb gather for t+1 (plain cached loads; in flight during poll)
    int tn = (t + 1 < S_LEN) ? (t + 1) : t;   // harmless dup on last step
    int idx1 = xseq[tn * 256 + g * 16 + l15];
    const float* er = emb + (size_t)idx1 * EMBED + w * 128 + l4 * 8;
    float4v e[8];
    #pragma unroll
    for (int kk = 0; kk < 4; kk++) {
      e[2 * kk]     = *(const float4v*)(er + kk * 32);
      e[2 * kk + 1] = *(const float4v*)(er + kk * 32 + 4);
    }
    // wait for the 16 producers of h_{t-1} in this group (padded flags)
    if (t > 0) {
      if (tid < 16) {
        u32* f = flag + (g * 16 + tid) * FLAG_STRIDE;
        while (__hip_atomic_load(f, __ATOMIC_RELAXED, __HIP_MEMORY_SCOPE_AGENT) < (u32)t) { }
      }
      __syncthreads();
    }
    // h loads (8 x 16B coherent, compiler-pipelined) + h-MFMA from registers
    const u16* hp = hbuf + (size_t)p * BH;
    short8v a[8];
    #pragma unroll
    for (int kq = 0; kq < 8; kq++)
      a[kq] = cohload16(hp, aoff + kq * 64);
    #pragma unroll
    for (int kq = 0; kq < 8; kq++)
      #pragma unroll
      for (int jj = 0; jj < 4; jj++)
        accp[jj] = __builtin_amdgcn_mfma_f32_16x16x32_bf16(a[kq], Wf[jj][kq], accp[jj], 0, 0, 0);
    // partials -> LDS
    #pragma unroll
    for (int jj = 0; jj < 4; jj++)
      #pragma unroll
      for (int q = 0; q < 4; q++)
        red[w][l4 * 4 + q][jj * 16 + l15] = accp[jj][q];
    __syncthreads();
    // reduce + tanh + stores: 128 threads, each owns (row r, cols c0..c0+8)
    if (tid < 128) {
      float th[8];
      #pragma unroll
      for (int i = 0; i < 8; i++) {
        int c = c0 + i;
        float s = red[0][r][c] + red[1][r][c] + red[2][r][c] + red[3][r][c] + bsum[i];
        float ex = __expf(-2.0f * fabsf(s));
        float v = (1.0f - ex) / (1.0f + ex);
        th[i] = copysignf(v, s);
      }
      float4v o0 = {th[0], th[1], th[2], th[3]};
      float4v o1 = {th[4], th[5], th[6], th[7]};
      float* op = outt + (size_t)(g * 16 + r) * HIDDEN + jt * 64 + c0;
      *(float4v*)op = o0;
      *(float4v*)(op + 4) = o1;
      ushort8v hv;
      #pragma unroll
      for (int i = 0; i < 8; i++) hv[i] = f2bf(th[i]);
      u16* hq = hbuf + (size_t)(p ^ 1) * BH;
      cohstore16(hq, ((g * 16 + r) * HIDDEN + jt * 64 + c0) * 2, hv);
    }
    asm volatile("s_waitcnt vmcnt(0)" ::: "memory");  // h stores at coherent point
    __syncthreads();                                  // all waves drained; red reusable
    if (tid == 0)
      __hip_atomic_store(&flag[(g * 16 + jt) * FLAG_STRIDE], (u32)(t + 1),
                         __ATOMIC_RELAXED, __HIP_MEMORY_SCOPE_AGENT);
    // xp-MFMA for t+1 (register-only, off critical path)
    #pragma unroll
    for (int jj = 0; jj < 4; jj++) xacc[jj] = float4v{0.f, 0.f, 0.f, 0.f};
    #pragma unroll
    for (int kk = 0; kk < 4; kk++) {
      short8v af = cvt8(e[2 * kk], e[2 * kk + 1]);
      #pragma unroll
      for (int jj = 0; jj < 4; jj++)
        xacc[jj] = __builtin_amdgcn_mfma_f32_16x16x32_bf16(af, Wihf[jj][kk], xacc[jj], 0, 0, 0);
    }
  }
}

extern "C" void kernel_launch(void* const* d_in, const int* in_sizes, int n_in,
                              void* d_out, int out_size, void* d_ws, size_t ws_size,
                              hipStream_t stream) {
  const int* xseq   = (const int*)d_in[0];
  const float* emb  = (const float*)d_in[1];
  const float* wih  = (const float*)d_in[2];
  const float* bih  = (const float*)d_in[3];
  const float* whh  = (const float*)d_in[4];
  const float* bhh  = (const float*)d_in[5];
  float* out = (float*)d_out;
  char* ws = (char*)d_ws;
  u16* hbuf = (u16*)ws;                       // 1,048,576 B (2 x 256 x 1024 bf16)
  u32* flag = (u32*)(ws + 1048576);           // 32,768 B (256 flags, 128B stride)

  prep_kernel<<<264, 256, 0, stream>>>(hbuf, flag);
  rnn_fused<<<256, 256, 0, stream>>>(xseq, emb, wih, bih, whh, bhh, hbuf, out, flag);
}

// Round 9
// 3975.195 us; speedup vs baseline: 1.1001x; 1.1001x over previous
//
#include <hip/hip_runtime.h>
#include <hip/hip_bf16.h>

typedef unsigned short u16;
typedef unsigned int u32;
typedef unsigned long long u64;
typedef __attribute__((ext_vector_type(8))) short short8v;      // MFMA bf16 frag (4 VGPR)
typedef __attribute__((ext_vector_type(8))) unsigned short ushort8v;
typedef __attribute__((ext_vector_type(4))) float float4v;
typedef __attribute__((ext_vector_type(4))) unsigned int uint4v;

#define S_LEN 1024
#define BATCH 256
#define VOCAB 32000
#define EMBED 512
#define HIDDEN 1024
#define BH (BATCH * HIDDEN)
#define FLAG_STRIDE 32   // u32s (128B) per flag: distinct L2/L3 lines

__device__ inline u16 f2bf(float f) {
  return __builtin_bit_cast(u16, __float2bfloat16(f));  // RNE
}

// Coherent (sc0|sc1 = cpol 17: L2-bypass, L3 coherent point) 16B ops.
__device__ inline short8v cohload16(const u16* base, int voff) {
  __amdgpu_buffer_rsrc_t r =
      __builtin_amdgcn_make_buffer_rsrc((void*)base, (short)0, -1, 0x00020000);
  uint4v d = __builtin_amdgcn_raw_buffer_load_b128(r, voff, 0, 17);
  return __builtin_bit_cast(short8v, d);
}
__device__ inline void cohstore16(u16* base, int voff, ushort8v v) {
  __amdgpu_buffer_rsrc_t r =
      __builtin_amdgcn_make_buffer_rsrc((void*)base, (short)0, -1, 0x00020000);
  __builtin_amdgcn_raw_buffer_store_b128(__builtin_bit_cast(uint4v, v), r, voff, 0, 17);
}

__device__ inline short8v cvt8(float4v a, float4v b) {
  ushort8v v;
  v[0]=f2bf(a[0]); v[1]=f2bf(a[1]); v[2]=f2bf(a[2]); v[3]=f2bf(a[3]);
  v[4]=f2bf(b[0]); v[5]=f2bf(b[1]); v[6]=f2bf(b[2]); v[7]=f2bf(b[3]);
  return __builtin_bit_cast(short8v, v);
}

// ---------------- prep: zero hbuf (1MB) + flags (128KB) ----------------
__global__ __launch_bounds__(256) void prep_kernel(u16* __restrict__ ws16) {
  int i = blockIdx.x * 256 + threadIdx.x;   // 73728 chunks of 16B
  ushort8v z = {0,0,0,0,0,0,0,0};
  *(ushort8v*)(ws16 + (size_t)i * 8) = z;
}

// ---------------- fused recurrence + input projection ----------------
// 256 persistent blocks = 16 groups (16 batch rows) x 16 col-tiles (64 cols).
// Per wave (k-split x4): W_hh quarter (128 VGPR) + W_ih quarter (64 VGPR) in
// registers. Per step: e-loads + per-wave 16-flag poll; h-loads issued, then
// xp-MFMA(t+1) in the load shadow; h-MFMA; 2-barrier LDS reduce; per-wave
// tanh/store/drain/publish. Exchange: sc0|sc1 write-through + value flags.
__global__ __launch_bounds__(256, 1) void rnn_fused(const int* __restrict__ xseq,
                                                    const float* __restrict__ emb,
                                                    const float* __restrict__ wih,
                                                    const float* __restrict__ bih,
                                                    const float* __restrict__ whh,
                                                    const float* __restrict__ bhh,
                                                    u16* __restrict__ hbuf,
                                                    float* __restrict__ out,
                                                    u32* __restrict__ flag) {
  __shared__ float red[4][16][68];     // [wave][row][col] fp32 partials (pad 68)
  __shared__ u16 xq[S_LEN * 16];       // [t][r] token ids (VOCAB<65536), 32KB
  const int tid = threadIdx.x;
  const int lane = tid & 63, w = tid >> 6;
  const int l15 = lane & 15, l4 = lane >> 4;
  const int g = blockIdx.x & 15;             // batch rows [g*16, g*16+16)
  const int jt = blockIdx.x >> 4;            // hidden cols [jt*64, jt*64+64)

  // ---- prologue ----
  short8v Wf[4][8];   // W_hh[col jt*64+jj*16+l15][k = w*256+kq*32+l4*8 ..+8]
  #pragma unroll
  for (int jj = 0; jj < 4; jj++)
    #pragma unroll
    for (int kq = 0; kq < 8; kq++) {
      const float* s = whh + (size_t)(jt * 64 + jj * 16 + l15) * HIDDEN
                       + w * 256 + kq * 32 + l4 * 8;
      Wf[jj][kq] = cvt8(*(const float4v*)s, *(const float4v*)(s + 4));
    }
  short8v Wihf[4][4]; // W_ih[col][k = w*128+kk*32+l4*8 ..+8]
  #pragma unroll
  for (int jj = 0; jj < 4; jj++)
    #pragma unroll
    for (int kk = 0; kk < 4; kk++) {
      const float* s = wih + (size_t)(jt * 64 + jj * 16 + l15) * EMBED
                       + w * 128 + kk * 32 + l4 * 8;
      Wihf[jj][kk] = cvt8(*(const float4v*)s, *(const float4v*)(s + 4));
    }
  // xseq slice -> LDS (u16)
  for (int i = tid; i < S_LEN * 16; i += 256)
    xq[i] = (u16)xseq[(i >> 4) * BATCH + g * 16 + (i & 15)];
  // tail ownership: lanes 0-31 of wave w own (row w*4+(lane>>3), cols (lane&7)*8..+8)
  const int trow = w * 4 + (lane >> 3);
  const int tc0 = (lane & 7) * 8;
  float bsum[8];
  #pragma unroll
  for (int i = 0; i < 8; i++)
    bsum[i] = bhh[jt * 64 + tc0 + i] + bih[jt * 64 + tc0 + i];
  const int aoff = ((g * 16 + l15) * HIDDEN + w * 256 + l4 * 8) * 2;
  __syncthreads();  // xq ready

  // ---- xp-partials for t=0 ----
  float4v xacc[4] = {};
  {
    const float* er = emb + (size_t)xq[l15] * EMBED + w * 128 + l4 * 8;
    #pragma unroll
    for (int kk = 0; kk < 4; kk++) {
      short8v af = cvt8(*(const float4v*)(er + kk * 32),
                        *(const float4v*)(er + kk * 32 + 4));
      #pragma unroll
      for (int jj = 0; jj < 4; jj++)
        xacc[jj] = __builtin_amdgcn_mfma_f32_16x16x32_bf16(af, Wihf[jj][kk], xacc[jj], 0, 0, 0);
    }
  }

  for (int t = 0; t < S_LEN; t++) {
    const int p = t & 1;
    float* outt = out + (size_t)t * BH;
    float4v accp[4] = {xacc[0], xacc[1], xacc[2], xacc[3]};
    // e-loads for t+1 (idx from LDS; in flight during poll)
    int tn = (t + 1 < S_LEN) ? (t + 1) : t;
    const float* er = emb + (size_t)xq[tn * 16 + l15] * EMBED + w * 128 + l4 * 8;
    float4v e[8];
    #pragma unroll
    for (int kk = 0; kk < 4; kk++) {
      e[2 * kk]     = *(const float4v*)(er + kk * 32);
      e[2 * kk + 1] = *(const float4v*)(er + kk * 32 + 4);
    }
    // per-wave poll: wave w needs producers jt' = w*4..w*4+3, waves 0..3 each
    if (t > 0) {
      if (lane < 16) {
        const u32* f = flag + ((size_t)(g * 16 + w * 4 + (lane >> 2)) * 4 + (lane & 3)) * FLAG_STRIDE;
        while (__hip_atomic_load(f, __ATOMIC_RELAXED, __HIP_MEMORY_SCOPE_AGENT) < (u32)t) { }
      }
    }
    __builtin_amdgcn_sched_barrier(0);  // pin h-loads after the poll
    // h loads (coherent, pipelined)
    const u16* hp = hbuf + (size_t)p * BH;
    short8v a[8];
    #pragma unroll
    for (int kq = 0; kq < 8; kq++)
      a[kq] = cohload16(hp, aoff + kq * 64);
    // xp-MFMA for t+1 in the h-load shadow (register-only)
    float4v xn[4] = {};
    #pragma unroll
    for (int kk = 0; kk < 4; kk++) {
      short8v af = cvt8(e[2 * kk], e[2 * kk + 1]);
      #pragma unroll
      for (int jj = 0; jj < 4; jj++)
        xn[jj] = __builtin_amdgcn_mfma_f32_16x16x32_bf16(af, Wihf[jj][kk], xn[jj], 0, 0, 0);
    }
    // h-MFMA
    #pragma unroll
    for (int kq = 0; kq < 8; kq++)
      #pragma unroll
      for (int jj = 0; jj < 4; jj++)
        accp[jj] = __builtin_amdgcn_mfma_f32_16x16x32_bf16(a[kq], Wf[jj][kq], accp[jj], 0, 0, 0);
    xacc[0] = xn[0]; xacc[1] = xn[1]; xacc[2] = xn[2]; xacc[3] = xn[3];
    // partials -> LDS
    #pragma unroll
    for (int jj = 0; jj < 4; jj++)
      #pragma unroll
      for (int q = 0; q < 4; q++)
        red[w][l4 * 4 + q][jj * 16 + l15] = accp[jj][q];
    __syncthreads();
    // reduce-read (lanes 0-31 per wave)
    float sum[8];
    if (lane < 32) {
      float4v r0 = *(const float4v*)&red[0][trow][tc0];
      float4v r1 = *(const float4v*)&red[0][trow][tc0 + 4];
      float4v s0 = *(const float4v*)&red[1][trow][tc0];
      float4v s1 = *(const float4v*)&red[1][trow][tc0 + 4];
      float4v u0 = *(const float4v*)&red[2][trow][tc0];
      float4v u1 = *(const float4v*)&red[2][trow][tc0 + 4];
      float4v v0 = *(const float4v*)&red[3][trow][tc0];
      float4v v1 = *(const float4v*)&red[3][trow][tc0 + 4];
      #pragma unroll
      for (int i = 0; i < 4; i++) {
        sum[i]     = r0[i] + s0[i] + u0[i] + v0[i] + bsum[i];
        sum[i + 4] = r1[i] + s1[i] + u1[i] + v1[i] + bsum[i + 4];
      }
    }
    __syncthreads();  // red free for next step
    // per-wave tail: tanh + fp32 out + coherent bf16 h store
    if (lane < 32) {
      float th[8];
      #pragma unroll
      for (int i = 0; i < 8; i++) {
        float ex = __expf(-2.0f * fabsf(sum[i]));
        float v = (1.0f - ex) / (1.0f + ex);
        th[i] = copysignf(v, sum[i]);
      }
      float4v o0 = {th[0], th[1], th[2], th[3]};
      float4v o1 = {th[4], th[5], th[6], th[7]};
      float* op = outt + (size_t)(g * 16 + trow) * HIDDEN + jt * 64 + tc0;
      *(float4v*)op = o0;
      *(float4v*)(op + 4) = o1;
      ushort8v hv;
      #pragma unroll
      for (int i = 0; i < 8; i++) hv[i] = f2bf(th[i]);
      u16* hq = hbuf + (size_t)(p ^ 1) * BH;
      cohstore16(hq, ((g * 16 + trow) * HIDDEN + jt * 64 + tc0) * 2, hv);
    }
    asm volatile("s_waitcnt vmcnt(0)" ::: "memory");  // wave's stores at L3
    if (lane == 0)
      __hip_atomic_store(flag + ((size_t)(g * 16 + jt) * 4 + w) * FLAG_STRIDE,
                         (u32)(t + 1), __ATOMIC_RELAXED, __HIP_MEMORY_SCOPE_AGENT);
  }
}

extern "C" void kernel_launch(void* const* d_in, const int* in_sizes, int n_in,
                              void* d_out, int out_size, void* d_ws, size_t ws_size,
                              hipStream_t stream) {
  const int* xseq   = (const int*)d_in[0];
  const float* emb  = (const float*)d_in[1];
  const float* wih  = (const float*)d_in[2];
  const float* bih  = (const float*)d_in[3];
  const float* whh  = (const float*)d_in[4];
  const float* bhh  = (const float*)d_in[5];
  float* out = (float*)d_out;
  char* ws = (char*)d_ws;
  u16* hbuf = (u16*)ws;                       // 1,048,576 B (2 x 256 x 1024 bf16)
  u32* flag = (u32*)(ws + 1048576);           // 131,072 B (1024 flags, 128B stride)

  prep_kernel<<<288, 256, 0, stream>>>((u16*)ws);   // zero hbuf + flags
  rnn_fused<<<256, 256, 0, stream>>>(xseq, emb, wih, bih, whh, bhh, hbuf, out, flag);
}

// Round 10
// 3342.229 us; speedup vs baseline: 1.3084x; 1.1894x over previous
//
#include <hip/hip_runtime.h>
#include <hip/hip_bf16.h>

typedef unsigned short u16;
typedef unsigned int u32;
typedef unsigned long long u64;
typedef __attribute__((ext_vector_type(8))) short short8v;      // MFMA bf16 frag (4 VGPR)
typedef __attribute__((ext_vector_type(8))) unsigned short ushort8v;
typedef __attribute__((ext_vector_type(4))) float float4v;
typedef __attribute__((ext_vector_type(4))) unsigned int uint4v;
typedef __attribute__((ext_vector_type(2))) unsigned int uint2v;

#define S_LEN 1024
#define BATCH 256
#define VOCAB 32000
#define EMBED 512
#define HIDDEN 1024
#define BH (BATCH * HIDDEN)
#define FLAG_STRIDE 32   // u32s (128B) per flag: distinct L3 lines

__device__ inline u16 f2bf(float f) {
  return __builtin_bit_cast(u16, __float2bfloat16(f));  // RNE
}

// Coherent (sc0|sc1 = cpol 17: L2-bypass, L3 coherent point) ops.
__device__ inline short8v cohload16(const u16* base, int voff) {
  __amdgpu_buffer_rsrc_t r =
      __builtin_amdgcn_make_buffer_rsrc((void*)base, (short)0, -1, 0x00020000);
  uint4v d = __builtin_amdgcn_raw_buffer_load_b128(r, voff, 0, 17);
  return __builtin_bit_cast(short8v, d);
}
__device__ inline void cohstore8(u16* base, int voff, uint2v v) {
  __amdgpu_buffer_rsrc_t r =
      __builtin_amdgcn_make_buffer_rsrc((void*)base, (short)0, -1, 0x00020000);
  __builtin_amdgcn_raw_buffer_store_b64(v, r, voff, 0, 17);
}

__device__ inline short8v cvt8(float4v a, float4v b) {
  ushort8v v;
  v[0]=f2bf(a[0]); v[1]=f2bf(a[1]); v[2]=f2bf(a[2]); v[3]=f2bf(a[3]);
  v[4]=f2bf(b[0]); v[5]=f2bf(b[1]); v[6]=f2bf(b[2]); v[7]=f2bf(b[3]);
  return __builtin_bit_cast(short8v, v);
}

// ---------------- prep: zero hbuf (1MB) + flags (128KB) ----------------
__global__ __launch_bounds__(256) void prep_kernel(u16* __restrict__ ws16) {
  int i = blockIdx.x * 256 + threadIdx.x;   // 73728 chunks of 16B
  ushort8v z = {0,0,0,0,0,0,0,0};
  *(ushort8v*)(ws16 + (size_t)i * 8) = z;
}

// ---------------- fused recurrence + input projection ----------------
// 256 persistent blocks = 16 groups (16 batch rows) x 16 col-tiles (64 cols).
// Per wave (k-split x4): W_hh quarter (128 VGPR) + W_ih quarter (64 VGPR) in
// registers. Per step: per-wave 16-flag poll; h-loads; THEN e-loads (t+1) so
// h-MFMA waits only vmcnt(8); 2-barrier LDS reduce; 64-lane tail (tanh + out
// + coherent h store); wave drain; per-wave flag publish; xp-MFMA for t+1
// after publish (overlaps next poll wait).
__global__ __launch_bounds__(256, 1) void rnn_fused(const int* __restrict__ xseq,
                                                    const float* __restrict__ emb,
                                                    const float* __restrict__ wih,
                                                    const float* __restrict__ bih,
                                                    const float* __restrict__ whh,
                                                    const float* __restrict__ bhh,
                                                    u16* __restrict__ hbuf,
                                                    float* __restrict__ out,
                                                    u32* __restrict__ flag) {
  __shared__ float red[4][16][68];     // [wave][row][col] fp32 partials (pad 68)
  __shared__ u16 xq[S_LEN * 16];       // [t][r] token ids (VOCAB<65536), 32KB
  const int tid = threadIdx.x;
  const int lane = tid & 63, w = tid >> 6;
  const int l15 = lane & 15, l4 = lane >> 4;
  const int g = blockIdx.x & 15;             // batch rows [g*16, g*16+16)
  const int jt = blockIdx.x >> 4;            // hidden cols [jt*64, jt*64+64)

  // ---- prologue ----
  short8v Wf[4][8];   // W_hh[col jt*64+jj*16+l15][k = w*256+kq*32+l4*8 ..+8]
  #pragma unroll
  for (int jj = 0; jj < 4; jj++)
    #pragma unroll
    for (int kq = 0; kq < 8; kq++) {
      const float* s = whh + (size_t)(jt * 64 + jj * 16 + l15) * HIDDEN
                       + w * 256 + kq * 32 + l4 * 8;
      Wf[jj][kq] = cvt8(*(const float4v*)s, *(const float4v*)(s + 4));
    }
  short8v Wihf[4][4]; // W_ih[col][k = w*128+kk*32+l4*8 ..+8]
  #pragma unroll
  for (int jj = 0; jj < 4; jj++)
    #pragma unroll
    for (int kk = 0; kk < 4; kk++) {
      const float* s = wih + (size_t)(jt * 64 + jj * 16 + l15) * EMBED
                       + w * 128 + kk * 32 + l4 * 8;
      Wihf[jj][kk] = cvt8(*(const float4v*)s, *(const float4v*)(s + 4));
    }
  // xseq slice -> LDS (u16)
  for (int i = tid; i < S_LEN * 16; i += 256)
    xq[i] = (u16)xseq[(i >> 4) * BATCH + g * 16 + (i & 15)];
  // tail ownership: all 64 lanes; row w*4+(lane>>4), cols (lane&15)*4 ..+4
  const int trow = w * 4 + (lane >> 4);
  const int tc4 = (lane & 15) * 4;
  float bsum[4];
  #pragma unroll
  for (int i = 0; i < 4; i++)
    bsum[i] = bhh[jt * 64 + tc4 + i] + bih[jt * 64 + tc4 + i];
  const int aoff = ((g * 16 + l15) * HIDDEN + w * 256 + l4 * 8) * 2;
  const int hoff = ((g * 16 + trow) * HIDDEN + jt * 64 + tc4) * 2;
  __syncthreads();  // xq ready

  // ---- xp-partials for t=0 ----
  float4v xacc[4] = {};
  {
    const float* er = emb + (size_t)xq[l15] * EMBED + w * 128 + l4 * 8;
    #pragma unroll
    for (int kk = 0; kk < 4; kk++) {
      short8v af = cvt8(*(const float4v*)(er + kk * 32),
                        *(const float4v*)(er + kk * 32 + 4));
      #pragma unroll
      for (int jj = 0; jj < 4; jj++)
        xacc[jj] = __builtin_amdgcn_mfma_f32_16x16x32_bf16(af, Wihf[jj][kk], xacc[jj], 0, 0, 0);
    }
  }

  for (int t = 0; t < S_LEN; t++) {
    const int p = t & 1;
    float* outt = out + (size_t)t * BH;
    float4v accp[4] = {xacc[0], xacc[1], xacc[2], xacc[3]};
    // per-wave poll: wave w needs producer blocks jt' = w*4..w*4+3, waves 0..3
    if (t > 0) {
      if (lane < 16) {
        const u32* f = flag + ((size_t)(g * 16 + w * 4 + (lane >> 2)) * 4 + (lane & 3)) * FLAG_STRIDE;
        while (__hip_atomic_load(f, __ATOMIC_RELAXED, __HIP_MEMORY_SCOPE_AGENT) < (u32)t) { }
      }
    }
    __builtin_amdgcn_sched_barrier(0);  // h-loads strictly after the poll
    // h loads FIRST (coherent; h-MFMA will wait only vmcnt(8))
    const u16* hp = hbuf + (size_t)p * BH;
    short8v a[8];
    #pragma unroll
    for (int kq = 0; kq < 8; kq++)
      a[kq] = cohload16(hp, aoff + kq * 64);
    __builtin_amdgcn_sched_barrier(0);  // e-loads strictly after h-loads
    // e-loads for t+1 (plain cached; drained by the pre-flag vmcnt(0))
    int tn = (t + 1 < S_LEN) ? (t + 1) : t;
    const float* er = emb + (size_t)xq[tn * 16 + l15] * EMBED + w * 128 + l4 * 8;
    float4v e[8];
    #pragma unroll
    for (int kk = 0; kk < 4; kk++) {
      e[2 * kk]     = *(const float4v*)(er + kk * 32);
      e[2 * kk + 1] = *(const float4v*)(er + kk * 32 + 4);
    }
    // h-MFMA
    #pragma unroll
    for (int kq = 0; kq < 8; kq++)
      #pragma unroll
      for (int jj = 0; jj < 4; jj++)
        accp[jj] = __builtin_amdgcn_mfma_f32_16x16x32_bf16(a[kq], Wf[jj][kq], accp[jj], 0, 0, 0);
    // partials -> LDS
    #pragma unroll
    for (int jj = 0; jj < 4; jj++)
      #pragma unroll
      for (int q = 0; q < 4; q++)
        red[w][l4 * 4 + q][jj * 16 + l15] = accp[jj][q];
    __syncthreads();
    // reduce-read: every lane owns (row trow, cols tc4..tc4+4)
    float4v r0 = *(const float4v*)&red[0][trow][tc4];
    float4v r1 = *(const float4v*)&red[1][trow][tc4];
    float4v r2 = *(const float4v*)&red[2][trow][tc4];
    float4v r3 = *(const float4v*)&red[3][trow][tc4];
    __syncthreads();  // red free for next step
    float th[4];
    #pragma unroll
    for (int i = 0; i < 4; i++) {
      float s = r0[i] + r1[i] + r2[i] + r3[i] + bsum[i];
      float ex = __expf(-2.0f * fabsf(s));
      float v = (1.0f - ex) / (1.0f + ex);
      th[i] = copysignf(v, s);
    }
    // stores: fp32 out (plain, 16B) + bf16 h (coherent, 8B)
    float4v o = {th[0], th[1], th[2], th[3]};
    *(float4v*)(outt + (size_t)(g * 16 + trow) * HIDDEN + jt * 64 + tc4) = o;
    uint2v hv;
    hv[0] = (u32)f2bf(th[0]) | ((u32)f2bf(th[1]) << 16);
    hv[1] = (u32)f2bf(th[2]) | ((u32)f2bf(th[3]) << 16);
    u16* hq = hbuf + (size_t)(p ^ 1) * BH;
    cohstore8(hq, hoff, hv);
    asm volatile("s_waitcnt vmcnt(0)" ::: "memory");  // h at L3 (+e-loads done)
    if (lane == 0)
      __hip_atomic_store(flag + ((size_t)(g * 16 + jt) * 4 + w) * FLAG_STRIDE,
                         (u32)(t + 1), __ATOMIC_RELAXED, __HIP_MEMORY_SCOPE_AGENT);
    // xp-MFMA for t+1 AFTER publish (overlaps next poll wait)
    float4v xn[4] = {};
    #pragma unroll
    for (int kk = 0; kk < 4; kk++) {
      short8v af = cvt8(e[2 * kk], e[2 * kk + 1]);
      #pragma unroll
      for (int jj = 0; jj < 4; jj++)
        xn[jj] = __builtin_amdgcn_mfma_f32_16x16x32_bf16(af, Wihf[jj][kk], xn[jj], 0, 0, 0);
    }
    xacc[0] = xn[0]; xacc[1] = xn[1]; xacc[2] = xn[2]; xacc[3] = xn[3];
  }
}

extern "C" void kernel_launch(void* const* d_in, const int* in_sizes, int n_in,
                              void* d_out, int out_size, void* d_ws, size_t ws_size,
                              hipStream_t stream) {
  const int* xseq   = (const int*)d_in[0];
  const float* emb  = (const float*)d_in[1];
  const float* wih  = (const float*)d_in[2];
  const float* bih  = (const float*)d_in[3];
  const float* whh  = (const float*)d_in[4];
  const float* bhh  = (const float*)d_in[5];
  float* out = (float*)d_out;
  char* ws = (char*)d_ws;
  u16* hbuf = (u16*)ws;                       // 1,048,576 B (2 x 256 x 1024 bf16)
  u32* flag = (u32*)(ws + 1048576);           // 131,072 B (1024 flags, 128B stride)

  prep_kernel<<<288, 256, 0, stream>>>((u16*)ws);   // zero hbuf + flags
  rnn_fused<<<256, 256, 0, stream>>>(xseq, emb, wih, bih, whh, bhh, hbuf, out, flag);
}